// Round 4
// baseline (424.623 us; speedup 1.0000x reference)
//
#include <hip/hip_runtime.h>
#include <math.h>

#define DIMC 256
#define HW   16384
#define NB   8
#define HID  512
#define NE   4
#define RNK  128

typedef __bf16 bf16x8 __attribute__((ext_vector_type(8)));
typedef float  f32x4  __attribute__((ext_vector_type(4)));

__device__ __forceinline__ unsigned short f2bf(float f) {
  unsigned u = __builtin_bit_cast(unsigned, f);
  u += 0x7FFFu + ((u >> 16) & 1u);          // round-to-nearest-even
  return (unsigned short)(u >> 16);
}
__device__ __forceinline__ unsigned pack2(float a, float b) {
  return (unsigned)f2bf(a) | ((unsigned)f2bf(b) << 16);
}

// ---------------------------------------------------------------------------
// Kernel 1: per-(b,c) plane: xsum = sum(x), hsum = sum(gelu(highpass3x3(x)))
// ---------------------------------------------------------------------------
__global__ __launch_bounds__(256) void k_conv_reduce(const float* __restrict__ x,
                                                     float* __restrict__ xsum,
                                                     float* __restrict__ hsum) {
  __shared__ float s[HW];
  const int p = blockIdx.x;
  const int tid = threadIdx.x;
  const float4* img4 = (const float4*)(x + (size_t)p * HW);
  float4* s4 = (float4*)s;
#pragma unroll
  for (int u = 0; u < 16; ++u) s4[tid + 256 * u] = img4[tid + 256 * u];
  __syncthreads();

  float xacc = 0.f, hacc = 0.f;
  for (int i = tid; i < HW; i += 256) {
    const int yy = i >> 7, xx = i & 127;
    const float c = s[i];
    float S = 0.f;
#pragma unroll
    for (int dy = -1; dy <= 1; ++dy) {
      const int y2 = yy + dy;
      if ((unsigned)y2 > 127u) continue;
      const int base = y2 << 7;
      if (xx > 0)   S += s[base + xx - 1];
      S += s[base + xx];
      if (xx < 127) S += s[base + xx + 1];
    }
    const float v = 9.f * c - S;
    hacc += 0.5f * v * (1.f + erff(v * 0.70710678118654752f));
    xacc += c;
  }
#pragma unroll
  for (int off = 32; off > 0; off >>= 1) {
    xacc += __shfl_down(xacc, off);
    hacc += __shfl_down(hacc, off);
  }
  __syncthreads();
  const int wid = tid >> 6, lane = tid & 63;
  if (lane == 0) { s[wid] = xacc; s[8 + wid] = hacc; }
  __syncthreads();
  if (tid == 0) {
    xsum[p] = s[0] + s[1] + s[2] + s[3];
    hsum[p] = s[8] + s[9] + s[10] + s[11];
  }
}

// ---------------------------------------------------------------------------
// Gating stage A: t1[b,o] = gelu( (hsum[b]·w1[o]) / 16384 + b1[o] )
// ---------------------------------------------------------------------------
__global__ __launch_bounds__(256) void k_gate_t1(
    const float* __restrict__ hsum, const float* __restrict__ w1,
    const float* __restrict__ b1, float* __restrict__ t1) {
  const int blk = blockIdx.x;
  const int b = blk >> 7;
  const int o = (blk & 127) * 4 + (threadIdx.x >> 6);
  const int lane = threadIdx.x & 63;
  const float4 h = *(const float4*)(hsum + b * DIMC + lane * 4);
  const float4 w = *(const float4*)(w1 + (size_t)o * DIMC + lane * 4);
  float acc = h.x * w.x + h.y * w.y + h.z * w.z + h.w * w.w;
#pragma unroll
  for (int off = 32; off > 0; off >>= 1) acc += __shfl_down(acc, off);
  if (lane == 0) {
    acc = acc * (1.f / 16384.f) + b1[o];
    t1[b * HID + o] = 0.5f * acc * (1.f + erff(acc * 0.70710678118654752f));
  }
}

// ---------------------------------------------------------------------------
// Gating stage B: fe[b,o] = t1[b]·w2[o] + b2[o]   (K=512)
// ---------------------------------------------------------------------------
__global__ __launch_bounds__(256) void k_gate_fe(
    const float* __restrict__ t1, const float* __restrict__ w2,
    const float* __restrict__ b2, float* __restrict__ fe) {
  const int blk = blockIdx.x;
  const int b = blk >> 6;
  const int o = (blk & 63) * 4 + (threadIdx.x >> 6);
  const int lane = threadIdx.x & 63;
  const float* tr = t1 + b * HID + lane * 8;
  const float* wr = w2 + (size_t)o * HID + lane * 8;
  const float4 ta = *(const float4*)tr,  tb = *(const float4*)(tr + 4);
  const float4 wa = *(const float4*)wr,  wb = *(const float4*)(wr + 4);
  float acc = ta.x * wa.x + ta.y * wa.y + ta.z * wa.z + ta.w * wa.w
            + tb.x * wb.x + tb.y * wb.y + tb.z * wb.z + tb.w * wb.w;
#pragma unroll
  for (int off = 32; off > 0; off >>= 1) acc += __shfl_down(acc, off);
  if (lane == 0) fe[b * DIMC + o] = acc + b2[o];
}

// ---------------------------------------------------------------------------
// Gating stage C: logits + softmax + top-2 (1 block, 4 waves: e = wave)
// ---------------------------------------------------------------------------
__global__ __launch_bounds__(256) void k_gate_fin(
    const float* __restrict__ xsum, const float* __restrict__ fe,
    const float* __restrict__ gw, const float* __restrict__ fgw,
    float* __restrict__ gates, float* __restrict__ gsumv, int* __restrict__ sel) {
  __shared__ float slog[NB][NE];
  const int wave = threadIdx.x >> 6, lane = threadIdx.x & 63;
  const int e = wave;
  const float4 g1 = *(const float4*)(gw + e * DIMC + lane * 4);
  const float4 g2 = *(const float4*)(fgw + e * DIMC + lane * 4);
  for (int b = 0; b < NB; ++b) {
    const float4 p = *(const float4*)(xsum + b * DIMC + lane * 4);
    const float4 f = *(const float4*)(fe + b * DIMC + lane * 4);
    float acc = (p.x * g1.x + p.y * g1.y + p.z * g1.z + p.w * g1.w) * (1.f / 16384.f)
              + f.x * g2.x + f.y * g2.y + f.z * g2.z + f.w * g2.w;
#pragma unroll
    for (int off = 32; off > 0; off >>= 1) acc += __shfl_down(acc, off);
    if (lane == 0) slog[b][e] = acc;
  }
  __syncthreads();
  if (threadIdx.x < NB) {
    const int b = threadIdx.x;
    float l[4] = {slog[b][0], slog[b][1], slog[b][2], slog[b][3]};
    const float m = fmaxf(fmaxf(l[0], l[1]), fmaxf(l[2], l[3]));
    float g[4];
    float ssum = 0.f;
    for (int e2 = 0; e2 < 4; ++e2) { g[e2] = expf(l[e2] - m); ssum += g[e2]; }
    for (int e2 = 0; e2 < 4; ++e2) g[e2] /= ssum;
    int i1 = 0;
    for (int e2 = 1; e2 < 4; ++e2) if (g[e2] > g[i1]) i1 = e2;
    int i2 = -1;
    for (int e2 = 0; e2 < 4; ++e2) {
      if (e2 == i1) continue;
      if (i2 < 0 || g[e2] > g[i2]) i2 = e2;
    }
    for (int e2 = 0; e2 < 4; ++e2)
      gates[b * 4 + e2] = (e2 == i1) ? g[i1] : ((e2 == i2) ? g[i2] : 0.f);
    gsumv[b] = g[i1] + g[i2];
    sel[b * 2 + 0] = i1;
    sel[b * 2 + 1] = i2;
  }
}

// ---------------------------------------------------------------------------
// Kernel 3: Q2[e,o,r] = sum_d Wp[o,d] * p2[e,d,r]   (fp32)
// ---------------------------------------------------------------------------
__global__ __launch_bounds__(128) void k_q2(const float* __restrict__ wp,
                                            const float* __restrict__ p2,
                                            float* __restrict__ q2) {
  const int eo = blockIdx.x;
  const int e = eo >> 8, o = eo & 255;
  const int r = threadIdx.x;
  const float* p2e = p2 + (size_t)e * DIMC * RNK;
  const float* wrow = wp + (size_t)o * DIMC;
  float acc = 0.f;
  for (int d = 0; d < DIMC; ++d) acc += wrow[d] * p2e[d * RNK + r];
  q2[(size_t)eo * RNK + r] = acc;
}

// ---------------------------------------------------------------------------
// Kernel 4: assemble per-batch bf16 GEMM weights (u32-pair packed writes)
// A1 [b][256][256] rows = p0[e1];p0[e2]
// A2 [b][256][256] rows = p1[e1];p1[e2]
// A3 [b][256][512] cols 0-255 = gate-scaled Q2, cols 256-511 = gsum*Wp
// ---------------------------------------------------------------------------
__global__ __launch_bounds__(256) void k_build(
    const float* __restrict__ p0, const float* __restrict__ p1,
    const float* __restrict__ wp, const float* __restrict__ q2,
    const float* __restrict__ gates, const float* __restrict__ gsumv,
    const int* __restrict__ sel,
    unsigned* __restrict__ A1u, unsigned* __restrict__ A2u,
    unsigned* __restrict__ A3u) {
  const int P1 = NB * 256 * 128;
  const int P2 = P1;
  const int P3 = NB * 256 * 256;
  for (int pi = blockIdx.x * 256 + threadIdx.x; pi < P1 + P2 + P3;
       pi += gridDim.x * 256) {
    if (pi < P1) {
      const int b = pi >> 15;
      const int row = (pi >> 7) & 255;
      const int d = (pi & 127) * 2;
      const int e = sel[b * 2 + (row >> 7)];
      const float* src = p0 + ((size_t)e * 128 + (row & 127)) * 256 + d;
      A1u[pi] = pack2(src[0], src[1]);
    } else if (pi < P1 + P2) {
      const int j = pi - P1;
      const int b = j >> 15;
      const int row = (j >> 7) & 255;
      const int d = (j & 127) * 2;
      const int e = sel[b * 2 + (row >> 7)];
      const float* src = p1 + ((size_t)e * 128 + (row & 127)) * 256 + d;
      A2u[j] = pack2(src[0], src[1]);
    } else {
      const int j = pi - P1 - P2;
      const int b = j >> 16;
      const int o = (j >> 8) & 255;
      const int c = (j & 255) * 2;
      float v0, v1;
      if (c < 256) {
        const int e = sel[b * 2 + (c >> 7)];
        const float gsc = gates[b * 4 + e];
        const float* qq = q2 + ((size_t)e * 256 + o) * RNK + (c & 127);
        v0 = gsc * qq[0]; v1 = gsc * qq[1];
      } else {
        const float gs = gsumv[b];
        const float* wr = wp + (size_t)o * DIMC + (c - 256);
        v0 = gs * wr[0]; v1 = gs * wr[1];
      }
      A3u[j] = pack2(v0, v1);
    }
  }
}

// ---------------------------------------------------------------------------
// Kernel 5: persistent pipelined MFMA main compute.
// 256 blocks (1/CU, bid&7 = batch -> XCD-affine weights), 8 waves, 8 tiles
// of 64 px each. Register prefetch of next tile crosses raw s_barriers;
// A3 fragments register-resident (no global loads in final GEMM phase).
// LDS granule layout per tensor: [dblk=d/8][px ^ (dblk&7)][8 bf16] = 32 KB.
// ---------------------------------------------------------------------------
__global__ __launch_bounds__(512, 2) void k_main_mfma(
    const float* __restrict__ x, const float* __restrict__ shr,
    const unsigned short* __restrict__ A1b, const unsigned short* __restrict__ A2b,
    const unsigned short* __restrict__ A3b, float* __restrict__ out) {
  __shared__ unsigned short XF[16384];      // x tile, 32 KB
  __shared__ unsigned short SF[16384];      // shared tile, then Y tile
  const int tid = threadIdx.x;
  const int b = blockIdx.x & 7;
  const int tg = blockIdx.x >> 3;           // 0..31
  const int wave = tid >> 6;
  const int lane = tid & 63;
  const int li = lane & 15;
  const int g  = lane >> 4;
  const int wrow = wave * 32;
  const int px = tid & 63;                  // staging: 1 px per lane
  const int dblk0 = tid >> 6;               // staging: 0..7
  const size_t bbase = (size_t)b * DIMC * HW;

  // ---- preload A3 fragments (K=512) into registers: 32 x bf16x8 ----
  bf16x8 a3[2][16];
  {
    const unsigned short* A0 = A3b + ((size_t)b * 256 + wrow + li) * 512 + g * 8;
#pragma unroll
    for (int rf = 0; rf < 2; ++rf)
#pragma unroll
      for (int ks = 0; ks < 16; ++ks)
        a3[rf][ks] = *(const bf16x8*)(A0 + rf * 16 * 512 + ks * 32);
  }

  const int be = (li ^ g) * 8 + g * 512;

  // ---- prologue: prefetch tile 0 into registers ----
  float rx[32], rs[32];
  {
    const float* xb = x   + bbase + (size_t)tg * 8 * 64 + px;
    const float* sb = shr + bbase + (size_t)tg * 8 * 64 + px;
#pragma unroll
    for (int pass = 0; pass < 4; ++pass) {
      const int db = pass * 8 + dblk0;
#pragma unroll
      for (int jj = 0; jj < 8; ++jj) {
        rx[pass * 8 + jj] = xb[(size_t)(db * 8 + jj) * HW];
        rs[pass * 8 + jj] = sb[(size_t)(db * 8 + jj) * HW];
      }
    }
  }

  for (int j = 0; j < 8; ++j) {
    const int tile = tg * 8 + j;
    const size_t pbase = bbase + (size_t)tile * 64;

    // ---- convert prefetched regs -> LDS (conflict-free full-granule b128) ----
#pragma unroll
    for (int pass = 0; pass < 4; ++pass) {
      const int db = pass * 8 + dblk0;
      const int o = db * 512 + ((px ^ (db & 7)) * 8);
      uint4 wv;
      wv.x = pack2(rx[pass*8+0], rx[pass*8+1]);
      wv.y = pack2(rx[pass*8+2], rx[pass*8+3]);
      wv.z = pack2(rx[pass*8+4], rx[pass*8+5]);
      wv.w = pack2(rx[pass*8+6], rx[pass*8+7]);
      *(uint4*)(&XF[o]) = wv;
      uint4 sv;
      sv.x = pack2(rs[pass*8+0], rs[pass*8+1]);
      sv.y = pack2(rs[pass*8+2], rs[pass*8+3]);
      sv.z = pack2(rs[pass*8+4], rs[pass*8+5]);
      sv.w = pack2(rs[pass*8+6], rs[pass*8+7]);
      *(uint4*)(&SF[o]) = sv;
    }
    asm volatile("s_waitcnt lgkmcnt(0)" ::: "memory");
    __builtin_amdgcn_sched_barrier(0);
    __builtin_amdgcn_s_barrier();
    __builtin_amdgcn_sched_barrier(0);

    // ---- GEMM2: bb = A2 @ shared ----
    f32x4 accB[2][4];
#pragma unroll
    for (int rf = 0; rf < 2; ++rf)
#pragma unroll
      for (int pb = 0; pb < 4; ++pb) accB[rf][pb] = (f32x4)0.f;
    {
      const unsigned short* A0 = A2b + ((size_t)b * 256 + wrow + li) * 256;
      const unsigned short* A1r = A0 + 16 * 256;
#pragma unroll
      for (int ks = 0; ks < 8; ++ks) {
        const int ib = ((ks & 1) ? (be ^ 32) : be) + ks * 2048;
        bf16x8 bf[4];
#pragma unroll
        for (int pb = 0; pb < 4; ++pb) bf[pb] = *(const bf16x8*)(&SF[ib + pb * 128]);
        bf16x8 a0 = *(const bf16x8*)(A0 + ks * 32 + g * 8);
        bf16x8 a1 = *(const bf16x8*)(A1r + ks * 32 + g * 8);
#pragma unroll
        for (int pb = 0; pb < 4; ++pb) {
          accB[0][pb] = __builtin_amdgcn_mfma_f32_16x16x32_bf16(a0, bf[pb], accB[0][pb], 0, 0, 0);
          accB[1][pb] = __builtin_amdgcn_mfma_f32_16x16x32_bf16(a1, bf[pb], accB[1][pb], 0, 0, 0);
        }
      }
    }

    // ---- GEMM1: a = A1 @ x ----
    f32x4 accA[2][4];
#pragma unroll
    for (int rf = 0; rf < 2; ++rf)
#pragma unroll
      for (int pb = 0; pb < 4; ++pb) accA[rf][pb] = (f32x4)0.f;
    {
      const unsigned short* A0 = A1b + ((size_t)b * 256 + wrow + li) * 256;
      const unsigned short* A1r = A0 + 16 * 256;
#pragma unroll
      for (int ks = 0; ks < 8; ++ks) {
        const int ib = ((ks & 1) ? (be ^ 32) : be) + ks * 2048;
        bf16x8 bf[4];
#pragma unroll
        for (int pb = 0; pb < 4; ++pb) bf[pb] = *(const bf16x8*)(&XF[ib + pb * 128]);
        bf16x8 a0 = *(const bf16x8*)(A0 + ks * 32 + g * 8);
        bf16x8 a1 = *(const bf16x8*)(A1r + ks * 32 + g * 8);
#pragma unroll
        for (int pb = 0; pb < 4; ++pb) {
          accA[0][pb] = __builtin_amdgcn_mfma_f32_16x16x32_bf16(a0, bf[pb], accA[0][pb], 0, 0, 0);
          accA[1][pb] = __builtin_amdgcn_mfma_f32_16x16x32_bf16(a1, bf[pb], accA[1][pb], 0, 0, 0);
        }
      }
    }
    __builtin_amdgcn_s_barrier();           // all SF reads retired everywhere

    // ---- y = a * silu(bb) -> SF ----
#pragma unroll
    for (int rf = 0; rf < 2; ++rf) {
      const int r0 = wrow + rf * 16 + g * 4;
      const int ydblk = r0 >> 3;
      const int ys = ydblk & 7;
      const int yoff = (g & 1) * 4;
#pragma unroll
      for (int pb = 0; pb < 4; ++pb) {
        const int p = pb * 16 + li;
        f32x4 aa = accA[rf][pb], bb = accB[rf][pb];
        float y0 = aa[0] * (bb[0] / (1.f + __expf(-bb[0])));
        float y1 = aa[1] * (bb[1] / (1.f + __expf(-bb[1])));
        float y2 = aa[2] * (bb[2] / (1.f + __expf(-bb[2])));
        float y3 = aa[3] * (bb[3] / (1.f + __expf(-bb[3])));
        const int idx = ydblk * 512 + ((p ^ ys) * 8) + yoff;
        uint2 w;
        w.x = pack2(y0, y1);
        w.y = pack2(y2, y3);
        *(uint2*)(&SF[idx]) = w;
      }
    }

    // ---- prefetch next tile (stays in flight across barriers/GEMM3) ----
    {
      const int tnext = (j < 7) ? (tile + 1) : tile;
      const float* xb = x   + bbase + (size_t)tnext * 64 + px;
      const float* sb = shr + bbase + (size_t)tnext * 64 + px;
#pragma unroll
      for (int pass = 0; pass < 4; ++pass) {
        const int db = pass * 8 + dblk0;
#pragma unroll
        for (int jj = 0; jj < 8; ++jj) {
          rx[pass * 8 + jj] = xb[(size_t)(db * 8 + jj) * HW];
          rs[pass * 8 + jj] = sb[(size_t)(db * 8 + jj) * HW];
        }
      }
    }
    asm volatile("s_waitcnt lgkmcnt(0)" ::: "memory");
    __builtin_amdgcn_sched_barrier(0);
    __builtin_amdgcn_s_barrier();
    __builtin_amdgcn_sched_barrier(0);

    // ---- GEMM3: out = A3(regs) @ [y; x]  (K = 512, no global loads) ----
    f32x4 accO[2][4];
#pragma unroll
    for (int rf = 0; rf < 2; ++rf)
#pragma unroll
      for (int pb = 0; pb < 4; ++pb) accO[rf][pb] = (f32x4)0.f;
#pragma unroll
    for (int ks = 0; ks < 16; ++ks) {
      const int kk = ks & 7;
      const unsigned short* Bsrc = (ks < 8) ? SF : XF;
      const int ib = ((kk & 1) ? (be ^ 32) : be) + kk * 2048;
      bf16x8 bf[4];
#pragma unroll
      for (int pb = 0; pb < 4; ++pb) bf[pb] = *(const bf16x8*)(&Bsrc[ib + pb * 128]);
#pragma unroll
      for (int pb = 0; pb < 4; ++pb) {
        accO[0][pb] = __builtin_amdgcn_mfma_f32_16x16x32_bf16(a3[0][ks], bf[pb], accO[0][pb], 0, 0, 0);
        accO[1][pb] = __builtin_amdgcn_mfma_f32_16x16x32_bf16(a3[1][ks], bf[pb], accO[1][pb], 0, 0, 0);
      }
    }

    // ---- store out (fp32) ----
    {
      float* obase = out + pbase;
#pragma unroll
      for (int rf = 0; rf < 2; ++rf) {
        const int r0 = wrow + rf * 16 + g * 4;
#pragma unroll
        for (int pb = 0; pb < 4; ++pb) {
          const int p = pb * 16 + li;
#pragma unroll
          for (int i = 0; i < 4; ++i)
            obase[(size_t)(r0 + i) * HW + p] = accO[rf][pb][i];
        }
      }
    }
    __builtin_amdgcn_s_barrier();           // protect XF/SF until all reads done
  }
}

// ---------------------------------------------------------------------------
extern "C" void kernel_launch(void* const* d_in, const int* in_sizes, int n_in,
                              void* d_out, int out_size, void* d_ws, size_t ws_size,
                              hipStream_t stream) {
  (void)in_sizes; (void)n_in; (void)out_size; (void)ws_size;
  const float* x   = (const float*)d_in[0];
  const float* shr = (const float*)d_in[1];
  const float* w1  = (const float*)d_in[2];
  const float* b1  = (const float*)d_in[3];
  const float* w2  = (const float*)d_in[4];
  const float* b2  = (const float*)d_in[5];
  const float* gw  = (const float*)d_in[6];
  const float* fgw = (const float*)d_in[7];
  const float* p0  = (const float*)d_in[8];
  const float* p1  = (const float*)d_in[9];
  const float* p2  = (const float*)d_in[10];
  const float* wp  = (const float*)d_in[11];
  float* out = (float*)d_out;

  float* ws    = (float*)d_ws;
  float* xsum  = ws;                         // 2048 f32
  float* hsum  = ws + 2048;                  // 2048 f32
  float* gates = ws + 4096;                  // 32 f32
  float* gsumv = ws + 4128;                  // 8 f32
  int*   sel   = (int*)(ws + 4136);          // 16 ints
  float* q2    = ws + 4152;                  // 131072 f32
  unsigned* A1u = (unsigned*)(ws + 135224);  // 262144 u32 (bf16 pairs)
  unsigned* A2u = A1u + NB * 256 * 128;      // 262144 u32
  unsigned* A3u = A2u + NB * 256 * 128;      // 524288 u32
  float* t1g   = (float*)(A3u + NB * 256 * 256);  // 4096 f32
  float* feg   = t1g + NB * HID;                  // 2048 f32

  k_conv_reduce<<<NB * DIMC, 256, 0, stream>>>(x, xsum, hsum);
  k_gate_t1<<<1024, 256, 0, stream>>>(hsum, w1, b1, t1g);
  k_gate_fe<<<512, 256, 0, stream>>>(t1g, w2, b2, feg);
  k_gate_fin<<<1, 256, 0, stream>>>(xsum, feg, gw, fgw, gates, gsumv, sel);
  k_q2<<<NE * DIMC, 128, 0, stream>>>(wp, p2, q2);
  k_build<<<512, 256, 0, stream>>>(p0, p1, wp, q2, gates, gsumv, sel, A1u, A2u, A3u);
  k_main_mfma<<<256, 512, 0, stream>>>(x, shr,
      (const unsigned short*)A1u, (const unsigned short*)A2u,
      (const unsigned short*)A3u, out);
}

// Round 5
// 323.195 us; speedup vs baseline: 1.3138x; 1.3138x over previous
//
#include <hip/hip_runtime.h>
#include <math.h>

#define DIMC 256
#define HW   16384
#define NB   8
#define HID  512
#define NE   4
#define RNK  128

typedef __bf16 bf16x8 __attribute__((ext_vector_type(8)));
typedef float  f32x4  __attribute__((ext_vector_type(4)));

__device__ __forceinline__ unsigned short f2bf(float f) {
  unsigned u = __builtin_bit_cast(unsigned, f);
  u += 0x7FFFu + ((u >> 16) & 1u);          // round-to-nearest-even
  return (unsigned short)(u >> 16);
}
__device__ __forceinline__ unsigned pack2(float a, float b) {
  return (unsigned)f2bf(a) | ((unsigned)f2bf(b) << 16);
}
__device__ __forceinline__ float bf2f(unsigned short u) {
  unsigned v = ((unsigned)u) << 16;
  return __builtin_bit_cast(float, v);
}

// ---------------------------------------------------------------------------
// Kernel 1: per-(b,c) plane: xsum = sum(x), hsum = sum(gelu(highpass3x3(x)))
// bf16 plane in LDS (34 KB -> 4 blocks/CU), 16-px segments via b128 reads.
// ---------------------------------------------------------------------------
#define CPAD 136
__global__ __launch_bounds__(256) void k_conv_reduce(const float* __restrict__ x,
                                                     float* __restrict__ xsum,
                                                     float* __restrict__ hsum) {
  __shared__ unsigned short sp[128 * CPAD];  // 34816 B
  __shared__ float red[8];
  const int p = blockIdx.x;
  const int tid = threadIdx.x;
  const float4* img4 = (const float4*)(x + (size_t)p * HW);
#pragma unroll
  for (int u = 0; u < 16; ++u) {
    const int unit = tid + 256 * u;          // 4096 float4 units
    const float4 v = img4[unit];
    const int row = unit >> 5, xq = unit & 31;
    uint2 w;
    w.x = pack2(v.x, v.y);
    w.y = pack2(v.z, v.w);
    *(uint2*)&sp[row * CPAD + xq * 4] = w;
  }
  __syncthreads();

  float xacc = 0.f, hacc = 0.f;
#pragma unroll
  for (int u = 0; u < 4; ++u) {
    const int seg = tid + 256 * u;           // 1024 segments: 128 rows x 8
    const int row = seg >> 3, x0 = (seg & 7) * 16;
    float S[16], c[16];
#pragma unroll
    for (int j = 0; j < 16; ++j) S[j] = 0.f;
#pragma unroll
    for (int dr = -1; dr <= 1; ++dr) {
      const int r2 = row + dr;
      float v[18];
      if ((unsigned)r2 <= 127u) {
        const unsigned short* rp = sp + r2 * CPAD + x0;
        const uint4 q0 = *(const uint4*)(rp);
        const uint4 q1 = *(const uint4*)(rp + 8);
        v[0]  = (x0 > 0)       ? bf2f(rp[-1]) : 0.f;
        v[17] = (x0 + 16 < 128) ? bf2f(rp[16]) : 0.f;
        v[1] = bf2f((unsigned short)(q0.x & 0xffff)); v[2] = bf2f((unsigned short)(q0.x >> 16));
        v[3] = bf2f((unsigned short)(q0.y & 0xffff)); v[4] = bf2f((unsigned short)(q0.y >> 16));
        v[5] = bf2f((unsigned short)(q0.z & 0xffff)); v[6] = bf2f((unsigned short)(q0.z >> 16));
        v[7] = bf2f((unsigned short)(q0.w & 0xffff)); v[8] = bf2f((unsigned short)(q0.w >> 16));
        v[9]  = bf2f((unsigned short)(q1.x & 0xffff)); v[10] = bf2f((unsigned short)(q1.x >> 16));
        v[11] = bf2f((unsigned short)(q1.y & 0xffff)); v[12] = bf2f((unsigned short)(q1.y >> 16));
        v[13] = bf2f((unsigned short)(q1.z & 0xffff)); v[14] = bf2f((unsigned short)(q1.z >> 16));
        v[15] = bf2f((unsigned short)(q1.w & 0xffff)); v[16] = bf2f((unsigned short)(q1.w >> 16));
      } else {
#pragma unroll
        for (int j = 0; j < 18; ++j) v[j] = 0.f;
      }
      if (dr == 0) {
#pragma unroll
        for (int j = 0; j < 16; ++j) c[j] = v[j + 1];
      }
#pragma unroll
      for (int j = 0; j < 16; ++j) S[j] += v[j] + v[j + 1] + v[j + 2];
    }
#pragma unroll
    for (int j = 0; j < 16; ++j) {
      const float h = 9.f * c[j] - S[j];     // 8*center - neighbors
      hacc += 0.5f * h * (1.f + erff(h * 0.70710678118654752f));
      xacc += c[j];
    }
  }
#pragma unroll
  for (int off = 32; off > 0; off >>= 1) {
    xacc += __shfl_down(xacc, off);
    hacc += __shfl_down(hacc, off);
  }
  const int wid = tid >> 6, lane = tid & 63;
  if (lane == 0) { red[wid] = xacc; red[4 + wid] = hacc; }
  __syncthreads();
  if (tid == 0) {
    xsum[p] = red[0] + red[1] + red[2] + red[3];
    hsum[p] = red[4] + red[5] + red[6] + red[7];
  }
}

// ---------------------------------------------------------------------------
// Gating stage A: t1[b,o] = gelu( (hsum[b]·w1[o]) / 16384 + b1[o] )
// ---------------------------------------------------------------------------
__global__ __launch_bounds__(256) void k_gate_t1(
    const float* __restrict__ hsum, const float* __restrict__ w1,
    const float* __restrict__ b1, float* __restrict__ t1) {
  const int blk = blockIdx.x;
  const int b = blk >> 7;
  const int o = (blk & 127) * 4 + (threadIdx.x >> 6);
  const int lane = threadIdx.x & 63;
  const float4 h = *(const float4*)(hsum + b * DIMC + lane * 4);
  const float4 w = *(const float4*)(w1 + (size_t)o * DIMC + lane * 4);
  float acc = h.x * w.x + h.y * w.y + h.z * w.z + h.w * w.w;
#pragma unroll
  for (int off = 32; off > 0; off >>= 1) acc += __shfl_down(acc, off);
  if (lane == 0) {
    acc = acc * (1.f / 16384.f) + b1[o];
    t1[b * HID + o] = 0.5f * acc * (1.f + erff(acc * 0.70710678118654752f));
  }
}

// ---------------------------------------------------------------------------
// Gating stage B: fe[b,o] = t1[b]·w2[o] + b2[o]   (K=512)
// ---------------------------------------------------------------------------
__global__ __launch_bounds__(256) void k_gate_fe(
    const float* __restrict__ t1, const float* __restrict__ w2,
    const float* __restrict__ b2, float* __restrict__ fe) {
  const int blk = blockIdx.x;
  const int b = blk >> 6;
  const int o = (blk & 63) * 4 + (threadIdx.x >> 6);
  const int lane = threadIdx.x & 63;
  const float* tr = t1 + b * HID + lane * 8;
  const float* wr = w2 + (size_t)o * HID + lane * 8;
  const float4 ta = *(const float4*)tr,  tb = *(const float4*)(tr + 4);
  const float4 wa = *(const float4*)wr,  wb = *(const float4*)(wr + 4);
  float acc = ta.x * wa.x + ta.y * wa.y + ta.z * wa.z + ta.w * wa.w
            + tb.x * wb.x + tb.y * wb.y + tb.z * wb.z + tb.w * wb.w;
#pragma unroll
  for (int off = 32; off > 0; off >>= 1) acc += __shfl_down(acc, off);
  if (lane == 0) fe[b * DIMC + o] = acc + b2[o];
}

// ---------------------------------------------------------------------------
// Gating stage C: logits + softmax + top-2 (1 block, 4 waves: e = wave)
// ---------------------------------------------------------------------------
__global__ __launch_bounds__(256) void k_gate_fin(
    const float* __restrict__ xsum, const float* __restrict__ fe,
    const float* __restrict__ gw, const float* __restrict__ fgw,
    float* __restrict__ gates, float* __restrict__ gsumv, int* __restrict__ sel) {
  __shared__ float slog[NB][NE];
  const int wave = threadIdx.x >> 6, lane = threadIdx.x & 63;
  const int e = wave;
  const float4 g1 = *(const float4*)(gw + e * DIMC + lane * 4);
  const float4 g2 = *(const float4*)(fgw + e * DIMC + lane * 4);
  for (int b = 0; b < NB; ++b) {
    const float4 p = *(const float4*)(xsum + b * DIMC + lane * 4);
    const float4 f = *(const float4*)(fe + b * DIMC + lane * 4);
    float acc = (p.x * g1.x + p.y * g1.y + p.z * g1.z + p.w * g1.w) * (1.f / 16384.f)
              + f.x * g2.x + f.y * g2.y + f.z * g2.z + f.w * g2.w;
#pragma unroll
    for (int off = 32; off > 0; off >>= 1) acc += __shfl_down(acc, off);
    if (lane == 0) slog[b][e] = acc;
  }
  __syncthreads();
  if (threadIdx.x < NB) {
    const int b = threadIdx.x;
    float l[4] = {slog[b][0], slog[b][1], slog[b][2], slog[b][3]};
    const float m = fmaxf(fmaxf(l[0], l[1]), fmaxf(l[2], l[3]));
    float g[4];
    float ssum = 0.f;
    for (int e2 = 0; e2 < 4; ++e2) { g[e2] = expf(l[e2] - m); ssum += g[e2]; }
    for (int e2 = 0; e2 < 4; ++e2) g[e2] /= ssum;
    int i1 = 0;
    for (int e2 = 1; e2 < 4; ++e2) if (g[e2] > g[i1]) i1 = e2;
    int i2 = -1;
    for (int e2 = 0; e2 < 4; ++e2) {
      if (e2 == i1) continue;
      if (i2 < 0 || g[e2] > g[i2]) i2 = e2;
    }
    for (int e2 = 0; e2 < 4; ++e2)
      gates[b * 4 + e2] = (e2 == i1) ? g[i1] : ((e2 == i2) ? g[i2] : 0.f);
    gsumv[b] = g[i1] + g[i2];
    sel[b * 2 + 0] = i1;
    sel[b * 2 + 1] = i2;
  }
}

// ---------------------------------------------------------------------------
// Kernel 3: Q2[e,o,r] = sum_d Wp[o,d] * p2[e,d,r]   (fp32)
// ---------------------------------------------------------------------------
__global__ __launch_bounds__(128) void k_q2(const float* __restrict__ wp,
                                            const float* __restrict__ p2,
                                            float* __restrict__ q2) {
  const int eo = blockIdx.x;
  const int e = eo >> 8, o = eo & 255;
  const int r = threadIdx.x;
  const float* p2e = p2 + (size_t)e * DIMC * RNK;
  const float* wrow = wp + (size_t)o * DIMC;
  float acc = 0.f;
  for (int d = 0; d < DIMC; ++d) acc += wrow[d] * p2e[d * RNK + r];
  q2[(size_t)eo * RNK + r] = acc;
}

// ---------------------------------------------------------------------------
// Kernel 4: assemble per-batch bf16 GEMM weights (u32-pair packed writes)
// A1 [b][256][256] rows = p0[e1];p0[e2]
// A2 [b][256][256] rows = p1[e1];p1[e2]
// A3 [b][256][512] cols 0-255 = gate-scaled Q2, cols 256-511 = gsum*Wp
// ---------------------------------------------------------------------------
__global__ __launch_bounds__(256) void k_build(
    const float* __restrict__ p0, const float* __restrict__ p1,
    const float* __restrict__ wp, const float* __restrict__ q2,
    const float* __restrict__ gates, const float* __restrict__ gsumv,
    const int* __restrict__ sel,
    unsigned* __restrict__ A1u, unsigned* __restrict__ A2u,
    unsigned* __restrict__ A3u) {
  const int P1 = NB * 256 * 128;
  const int P2 = P1;
  const int P3 = NB * 256 * 256;
  for (int pi = blockIdx.x * 256 + threadIdx.x; pi < P1 + P2 + P3;
       pi += gridDim.x * 256) {
    if (pi < P1) {
      const int b = pi >> 15;
      const int row = (pi >> 7) & 255;
      const int d = (pi & 127) * 2;
      const int e = sel[b * 2 + (row >> 7)];
      const float* src = p0 + ((size_t)e * 128 + (row & 127)) * 256 + d;
      A1u[pi] = pack2(src[0], src[1]);
    } else if (pi < P1 + P2) {
      const int j = pi - P1;
      const int b = j >> 15;
      const int row = (j >> 7) & 255;
      const int d = (j & 127) * 2;
      const int e = sel[b * 2 + (row >> 7)];
      const float* src = p1 + ((size_t)e * 128 + (row & 127)) * 256 + d;
      A2u[j] = pack2(src[0], src[1]);
    } else {
      const int j = pi - P1 - P2;
      const int b = j >> 16;
      const int o = (j >> 8) & 255;
      const int c = (j & 255) * 2;
      float v0, v1;
      if (c < 256) {
        const int e = sel[b * 2 + (c >> 7)];
        const float gsc = gates[b * 4 + e];
        const float* qq = q2 + ((size_t)e * 256 + o) * RNK + (c & 127);
        v0 = gsc * qq[0]; v1 = gsc * qq[1];
      } else {
        const float gs = gsumv[b];
        const float* wr = wp + (size_t)o * DIMC + (c - 256);
        v0 = gs * wr[0]; v1 = gs * wr[1];
      }
      A3u[j] = pack2(v0, v1);
    }
  }
}

// ---------------------------------------------------------------------------
// Kernel 5: MFMA main compute. 1024 thr (16 waves, 16 rows/wave), 64-px tile,
// one tile per block (2048 blocks, 2 blocks/CU, 32 waves/CU).
// LDS layout per tensor: [dblk=d/8][px ^ (dblk&7)][8 bf16] = 32 KB.
// Staging: scalar column loads -> full-granule ds_write_b128 (conflict-free).
// ---------------------------------------------------------------------------
__global__ __launch_bounds__(1024, 8) void k_main_mfma(
    const float* __restrict__ x, const float* __restrict__ shr,
    const unsigned short* __restrict__ A1b, const unsigned short* __restrict__ A2b,
    const unsigned short* __restrict__ A3b, float* __restrict__ out) {
  __shared__ unsigned short XF[16384];      // x tile, 32 KB
  __shared__ unsigned short SF[16384];      // shared tile, then Y tile
  const int tid = threadIdx.x;
  const int b = blockIdx.x & 7;             // batch -> XCD affinity
  const int tile = blockIdx.x >> 3;         // 0..255
  const int nb0 = tile * 64;
  const int wave = tid >> 6;                // 0..15
  const int lane = tid & 63;
  const int li = lane & 15;
  const int g  = lane >> 4;
  const int wrow = wave * 16;
  const size_t pbase = (size_t)b * DIMC * HW + nb0;

  // ---- stage x, shr (transpose-on-load, conflict-free b128 writes) ----
  {
    const int px = tid & 63;
    const int slot = tid >> 6;              // 0..15
#pragma unroll
    for (int pass = 0; pass < 2; ++pass) {
      const int dblk = pass * 16 + slot;    // 0..31
      const float* xc = x   + pbase + (size_t)(dblk * 8) * HW + px;
      const float* sc = shr + pbase + (size_t)(dblk * 8) * HW + px;
      float vx[8], vs[8];
#pragma unroll
      for (int jj = 0; jj < 8; ++jj) {
        vx[jj] = xc[(size_t)jj * HW];
        vs[jj] = sc[(size_t)jj * HW];
      }
      const int o = dblk * 512 + ((px ^ (dblk & 7)) << 3);
      uint4 wv;
      wv.x = pack2(vx[0], vx[1]); wv.y = pack2(vx[2], vx[3]);
      wv.z = pack2(vx[4], vx[5]); wv.w = pack2(vx[6], vx[7]);
      *(uint4*)&XF[o] = wv;
      uint4 sv;
      sv.x = pack2(vs[0], vs[1]); sv.y = pack2(vs[2], vs[3]);
      sv.z = pack2(vs[4], vs[5]); sv.w = pack2(vs[6], vs[7]);
      *(uint4*)&SF[o] = sv;
    }
  }
  __syncthreads();

  // ---- GEMM2: bb = A2 @ shared ----
  f32x4 accB[4], accA[4];
#pragma unroll
  for (int pb = 0; pb < 4; ++pb) { accB[pb] = (f32x4)0.f; accA[pb] = (f32x4)0.f; }
  {
    const unsigned short* Arow = A2b + ((size_t)b * 256 + wrow + li) * 256 + g * 8;
#pragma unroll
    for (int ks = 0; ks < 8; ++ks) {
      const int dblkb = ks * 4 + g;
      const int ebase = dblkb * 512 + ((li ^ (dblkb & 7)) << 3);
      const bf16x8 a0 = *(const bf16x8*)(Arow + ks * 32);
#pragma unroll
      for (int pb = 0; pb < 4; ++pb) {
        const bf16x8 bf = *(const bf16x8*)&SF[ebase + pb * 128];
        accB[pb] = __builtin_amdgcn_mfma_f32_16x16x32_bf16(a0, bf, accB[pb], 0, 0, 0);
      }
    }
  }
  // ---- GEMM1: a = A1 @ x ----
  {
    const unsigned short* Arow = A1b + ((size_t)b * 256 + wrow + li) * 256 + g * 8;
#pragma unroll
    for (int ks = 0; ks < 8; ++ks) {
      const int dblkb = ks * 4 + g;
      const int ebase = dblkb * 512 + ((li ^ (dblkb & 7)) << 3);
      const bf16x8 a0 = *(const bf16x8*)(Arow + ks * 32);
#pragma unroll
      for (int pb = 0; pb < 4; ++pb) {
        const bf16x8 bf = *(const bf16x8*)&XF[ebase + pb * 128];
        accA[pb] = __builtin_amdgcn_mfma_f32_16x16x32_bf16(a0, bf, accA[pb], 0, 0, 0);
      }
    }
  }
  __syncthreads();                          // all SF reads done

  // ---- y = a * silu(bb) -> SF ----
  {
    const int ydblk = 2 * wave + (g >> 1);
    const int ys = ydblk & 7;
    const int yoff = (g & 1) * 4;
#pragma unroll
    for (int pb = 0; pb < 4; ++pb) {
      const int pxy = pb * 16 + li;
      const f32x4 aa = accA[pb], bb = accB[pb];
      const float y0 = aa[0] * (bb[0] / (1.f + __expf(-bb[0])));
      const float y1 = aa[1] * (bb[1] / (1.f + __expf(-bb[1])));
      const float y2 = aa[2] * (bb[2] / (1.f + __expf(-bb[2])));
      const float y3 = aa[3] * (bb[3] / (1.f + __expf(-bb[3])));
      uint2 w;
      w.x = pack2(y0, y1);
      w.y = pack2(y2, y3);
      *(uint2*)&SF[ydblk * 512 + ((pxy ^ ys) << 3) + yoff] = w;
    }
  }
  __syncthreads();                          // Y ready

  // ---- GEMM3: out = A3 @ [y; x]  (K = 512) ----
  f32x4 accO[4];
#pragma unroll
  for (int pb = 0; pb < 4; ++pb) accO[pb] = (f32x4)0.f;
  {
    const unsigned short* Arow = A3b + ((size_t)b * 256 + wrow + li) * 512 + g * 8;
#pragma unroll
    for (int ks = 0; ks < 16; ++ks) {
      const int kk = ks & 7;
      const unsigned short* Bsrc = (ks < 8) ? SF : XF;
      const int dblkb = kk * 4 + g;
      const int ebase = dblkb * 512 + ((li ^ (dblkb & 7)) << 3);
      const bf16x8 a0 = *(const bf16x8*)(Arow + ks * 32);
#pragma unroll
      for (int pb = 0; pb < 4; ++pb) {
        const bf16x8 bf = *(const bf16x8*)&Bsrc[ebase + pb * 128];
        accO[pb] = __builtin_amdgcn_mfma_f32_16x16x32_bf16(a0, bf, accO[pb], 0, 0, 0);
      }
    }
  }

  // ---- store out (fp32) ----
  {
    float* obase = out + pbase;
    const int r0 = wrow + g * 4;
#pragma unroll
    for (int pb = 0; pb < 4; ++pb) {
      const int p = pb * 16 + li;
#pragma unroll
      for (int i = 0; i < 4; ++i)
        obase[(size_t)(r0 + i) * HW + p] = accO[pb][i];
    }
  }
}

// ---------------------------------------------------------------------------
extern "C" void kernel_launch(void* const* d_in, const int* in_sizes, int n_in,
                              void* d_out, int out_size, void* d_ws, size_t ws_size,
                              hipStream_t stream) {
  (void)in_sizes; (void)n_in; (void)out_size; (void)ws_size;
  const float* x   = (const float*)d_in[0];
  const float* shr = (const float*)d_in[1];
  const float* w1  = (const float*)d_in[2];
  const float* b1  = (const float*)d_in[3];
  const float* w2  = (const float*)d_in[4];
  const float* b2  = (const float*)d_in[5];
  const float* gw  = (const float*)d_in[6];
  const float* fgw = (const float*)d_in[7];
  const float* p0  = (const float*)d_in[8];
  const float* p1  = (const float*)d_in[9];
  const float* p2  = (const float*)d_in[10];
  const float* wp  = (const float*)d_in[11];
  float* out = (float*)d_out;

  float* ws    = (float*)d_ws;
  float* xsum  = ws;                         // 2048 f32
  float* hsum  = ws + 2048;                  // 2048 f32
  float* gates = ws + 4096;                  // 32 f32
  float* gsumv = ws + 4128;                  // 8 f32
  int*   sel   = (int*)(ws + 4136);          // 16 ints
  float* q2    = ws + 4152;                  // 131072 f32
  unsigned* A1u = (unsigned*)(ws + 135224);  // 262144 u32 (bf16 pairs)
  unsigned* A2u = A1u + NB * 256 * 128;      // 262144 u32
  unsigned* A3u = A2u + NB * 256 * 128;      // 524288 u32
  float* t1g   = (float*)(A3u + NB * 256 * 256);  // 4096 f32
  float* feg   = t1g + NB * HID;                  // 2048 f32

  k_conv_reduce<<<NB * DIMC, 256, 0, stream>>>(x, xsum, hsum);
  k_gate_t1<<<1024, 256, 0, stream>>>(hsum, w1, b1, t1g);
  k_gate_fe<<<512, 256, 0, stream>>>(t1g, w2, b2, feg);
  k_gate_fin<<<1, 256, 0, stream>>>(xsum, feg, gw, fgw, gates, gsumv, sel);
  k_q2<<<NE * DIMC, 128, 0, stream>>>(wp, p2, q2);
  k_build<<<512, 256, 0, stream>>>(p0, p1, wp, q2, gates, gsumv, sel, A1u, A2u, A3u);
  k_main_mfma<<<2048, 1024, 0, stream>>>(x, shr,
      (const unsigned short*)A1u, (const unsigned short*)A2u,
      (const unsigned short*)A3u, out);
}